// Round 14
// baseline (135.857 us; speedup 1.0000x reference)
//
#include <hip/hip_runtime.h>
#include <hip/hip_bf16.h>
#include <math.h>

#define HD    128
#define NQH   32
#define NKVH  8
#define GQA   4
#define PBLK  16
#define L2_10000 13.287712379549449f   // log2(10000)
#define NEGBIG (-1.0e9f)               // inf-free "minus infinity"

typedef float f4    __attribute__((ext_vector_type(4)));
typedef float f32x4 __attribute__((ext_vector_type(4)));
typedef short bf8   __attribute__((ext_vector_type(8)));   // 8 bf16 = 4 VGPR

// RNE f32->bf16 via compiler (m240: do NOT hand-write cvt_pk inline asm)
__device__ __forceinline__ bf8 pack8(const float* v) {
    union { __hip_bfloat16 h[8]; bf8 b; } t;
#pragma unroll
    for (int j = 0; j < 8; ++j) t.h[j] = __float2bfloat16(v[j]);
    return t.b;
}

// interleaved rope table: tab[t*128 + 2f] = cos(t*invf_f), +1 = sin
__global__ void rope_table_kernel(float* __restrict__ tab, int T) {
    int idx = blockIdx.x * blockDim.x + threadIdx.x;
    int total = (T + 1) * 64;
    if (idx >= total) return;
    int t = idx >> 6, f = idx & 63;
    float invf = exp2f(-(float)f * (L2_10000 / 64.0f));
    float ss, cc;
    sincosf((float)t * invf, &ss, &cc);
    tab[(size_t)t * 128 + 2 * f]     = cc;
    tab[(size_t)t * 128 + 2 * f + 1] = ss;
}

// MFMA QK^T (verified r13) + register page-table addressing (no LDS in the
// address chain) + coalesced f4 V rows + VALU PV via LDS P-broadcast.
// Rounds 2-13 were pinned at ~13 GB/s/CU (latency x ~75 lines in flight);
// this keeps ~40 independent VMEM instrs in flight per wave.
__global__ __launch_bounds__(256) void paged_attn_kernel(
    const float* __restrict__ q,
    const float* __restrict__ kcur,
    const float* __restrict__ vcur,
    const float* __restrict__ kc,
    const float* __restrict__ vc,
    const int* __restrict__ bt,
    const float* __restrict__ tab,
    float* __restrict__ out,       // S==1
    float* __restrict__ pm,        // [nblk][4]
    float* __restrict__ pl,
    float* __restrict__ po,        // [nblk][4][HD]
    int T, int nb, int S, int useTable)
{
    const int bh  = blockIdx.x / S;
    const int sp  = blockIdx.x - bh * S;
    const int b   = bh >> 3, h = bh & 7;
    const int tid = threadIdx.x;
    const int w   = tid >> 6;       // wave 0..3
    const int l   = tid & 63;
    const int c   = l & 15;         // head col (scores) / token-in-tile (K rows)
    const int u   = l >> 4;         // 0..3
    const int hw2 = l >> 5;         // halfwave 0/1 (V/PV token split)

    __shared__ float qsm[4 * HD];
    __shared__ float smw[4][4], slw[4][4];
    __shared__ float sO[4][4][HD];
    __shared__ float sP[4][32][4];   // per-wave P staging [token][head]

    {   // rope current q (4 heads), fold in 128^-0.5
        const int g = tid >> 6, f = tid & 63;
        const float* qb = q + ((size_t)b * NQH + h * GQA + g) * HD;
        float xlo = qb[f], xhi = qb[64 + f];
        float cc, ss;
        if (useTable) { cc = tab[(size_t)T * 128 + 2 * f]; ss = tab[(size_t)T * 128 + 2 * f + 1]; }
        else { float invf = exp2f(-(float)f * (L2_10000 / 64.f)); sincosf((float)T * invf, &ss, &cc); }
        const float scale = 0.08838834764831845f;
        qsm[g * HD + f]      = (xlo * cc - xhi * ss) * scale;
        qsm[g * HD + 64 + f] = (xhi * cc + xlo * ss) * scale;
    }
    __syncthreads();

    // Q B-frags: col=c (head, 0 for c>=4), k = u*8 + 32*s4 + j   (r13 verbatim)
    bf8 qf[4];
    {
        float tv[8];
#pragma unroll
        for (int s4 = 0; s4 < 4; ++s4) {
            const int db = u * 8 + 32 * s4;
#pragma unroll
            for (int j = 0; j < 8; ++j) tv[j] = (c < 4) ? qsm[c * HD + db + j] : 0.f;
            qf[s4] = pack8(tv);
        }
    }

    const int total = T + 1;
    const int chunk = (((total + S - 1) / S) + 31) & ~31;   // 32-aligned splits
    const int lo = sp * chunk;
    const int hi = min(lo + chunk, total);
    const int page0 = lo >> 4;
    const bool useReg = ((chunk >> 4) + 2) <= 64;   // page table fits in 64 lanes

    // per-lane page table: byte offset of page (page0+l) in kc/vc
    unsigned pgoff;
    {
        int pidx = min(page0 + l, nb - 1);
        pgoff = (unsigned)bt[(size_t)b * nb + pidx] * (unsigned)(PBLK * NKVH * HD * 4);
    }
    const char* kcB = (const char*)kc;
    const char* vcB = (const char*)vc;
    const char* kcurB = (const char*)(kcur + ((size_t)b * NKVH + h) * HD);
    const char* vcurB = (const char*)(vcur + ((size_t)b * NKVH + h) * HD);
    const unsigned hoff = (unsigned)h * 512u;

    float invfA[8], invfB[8];
    if (!useTable) {
#pragma unroll
        for (int j = 0; j < 8; ++j) {
            invfA[j] = exp2f(-(float)(u * 8 + j) * (L2_10000 / 64.f));
            invfB[j] = exp2f(-(float)(32 + u * 8 + j) * (L2_10000 / 64.f));
        }
    }

    float m_run = NEGBIG, l_run = 0.f;
    f4 o0 = {0,0,0,0}, o1 = {0,0,0,0}, o2 = {0,0,0,0}, o3 = {0,0,0,0};

    for (int tok0 = lo + w * 32; tok0 < hi; tok0 += 128) {
        const bool tail = (tok0 + 32 > hi);

        // ---- V row addresses + issue first batch (deepest in flight) ----
        unsigned offV;
        {
            int pgu = ((tok0 + hw2 * 16) >> 4) - page0;
            offV = useReg ? (unsigned)__shfl((int)pgoff, pgu)
                          : (unsigned)bt[(size_t)b * nb + min(pgu + page0, nb - 1)] * 65536u;
        }
        const char* vrow0  = vcB + offV + hoff + (unsigned)((l & 31) * 16);
        const char* vcur_l = vcurB + (l & 31) * 16;
        f4 vvA[8], vvB[8];
#pragma unroll
        for (int i = 0; i < 8; ++i) {
            int tv = tok0 + hw2 * 16 + i;
            vvA[i] = *(const f4*)((tv >= T) ? vcur_l : (vrow0 + i * 4096));
        }

        f32x4 sa = {0.f, 0.f, 0.f, 0.f}, sb = {0.f, 0.f, 0.f, 0.f};
#pragma unroll
        for (int tile = 0; tile < 2; ++tile) {
            const int tA  = tok0 + tile * 16 + c;
            const int tAc = min(tA, T);
            const float* kb;
            {
                int pgu = ((tok0 + tile * 16) >> 4) - page0;
                unsigned off = useReg ? (unsigned)__shfl((int)pgoff, pgu)
                                      : (unsigned)bt[(size_t)b * nb + min(pgu + page0, nb - 1)] * 65536u;
                const char* ka = kcB + off + (unsigned)((tAc & 15) * 4096) + hoff;
                if (tAc == T) ka = kcurB;
                kb = (const float*)ka;
            }
            f4 k0a = *(const f4*)(kb + u * 8);
            f4 k0b = *(const f4*)(kb + u * 8 + 4);
            f4 k1a = *(const f4*)(kb + 32 + u * 8);
            f4 k1b = *(const f4*)(kb + 32 + u * 8 + 4);
            f4 k2a = *(const f4*)(kb + 64 + u * 8);
            f4 k2b = *(const f4*)(kb + 64 + u * 8 + 4);
            f4 k3a = *(const f4*)(kb + 96 + u * 8);
            f4 k3b = *(const f4*)(kb + 96 + u * 8 + 4);
            float cs0[16], cs1[16];
            if (useTable) {
                const float* tb = tab + (size_t)tAc * 128;
#pragma unroll
                for (int i = 0; i < 4; ++i) {
                    f4 x = *(const f4*)(tb + u * 16 + 4 * i);
                    cs0[4 * i] = x.x; cs0[4 * i + 1] = x.y; cs0[4 * i + 2] = x.z; cs0[4 * i + 3] = x.w;
                    f4 y = *(const f4*)(tb + 64 + u * 16 + 4 * i);
                    cs1[4 * i] = y.x; cs1[4 * i + 1] = y.y; cs1[4 * i + 2] = y.z; cs1[4 * i + 3] = y.w;
                }
            } else {
#pragma unroll
                for (int j = 0; j < 8; ++j) {
                    sincosf((float)tAc * invfA[j], &cs0[2 * j + 1], &cs0[2 * j]);
                    sincosf((float)tAc * invfB[j], &cs1[2 * j + 1], &cs1[2 * j]);
                }
            }
            float lo0[8], lo1[8], hi0[8], hi1[8];
#pragma unroll
            for (int j = 0; j < 8; ++j) {
                float a0 = (j < 4) ? k0a[j] : k0b[j - 4];
                float h0 = (j < 4) ? k2a[j] : k2b[j - 4];
                float a1 = (j < 4) ? k1a[j] : k1b[j - 4];
                float h1 = (j < 4) ? k3a[j] : k3b[j - 4];
                float c0 = cs0[2 * j], s0 = cs0[2 * j + 1];
                float c1 = cs1[2 * j], s1 = cs1[2 * j + 1];
                lo0[j] = a0 * c0 - h0 * s0;  hi0[j] = h0 * c0 + a0 * s0;
                lo1[j] = a1 * c1 - h1 * s1;  hi1[j] = h1 * c1 + a1 * s1;
            }
            bf8 f0 = pack8(lo0), f1 = pack8(lo1), f2 = pack8(hi0), f3 = pack8(hi1);
            if (tile == 0) {
                sa = __builtin_amdgcn_mfma_f32_16x16x32_bf16(f0, qf[0], sa, 0, 0, 0);
                sa = __builtin_amdgcn_mfma_f32_16x16x32_bf16(f1, qf[1], sa, 0, 0, 0);
                sa = __builtin_amdgcn_mfma_f32_16x16x32_bf16(f2, qf[2], sa, 0, 0, 0);
                sa = __builtin_amdgcn_mfma_f32_16x16x32_bf16(f3, qf[3], sa, 0, 0, 0);
                // issue second V batch while tile1's K loads go out
#pragma unroll
                for (int i = 0; i < 8; ++i) {
                    int tv = tok0 + hw2 * 16 + 8 + i;
                    vvB[i] = *(const f4*)((tv >= T) ? vcur_l : (vrow0 + (8 + i) * 4096));
                }
            } else {
                sb = __builtin_amdgcn_mfma_f32_16x16x32_bf16(f0, qf[0], sb, 0, 0, 0);
                sb = __builtin_amdgcn_mfma_f32_16x16x32_bf16(f1, qf[1], sb, 0, 0, 0);
                sb = __builtin_amdgcn_mfma_f32_16x16x32_bf16(f2, qf[2], sb, 0, 0, 0);
                sb = __builtin_amdgcn_mfma_f32_16x16x32_bf16(f3, qf[3], sb, 0, 0, 0);
            }
        }

        if (tail) {   // mask tokens >= hi (inf-free)  (r13 verbatim)
#pragma unroll
            for (int r = 0; r < 4; ++r) {
                if (tok0 + u * 4 + r      >= hi) sa[r] = NEGBIG;
                if (tok0 + 16 + u * 4 + r >= hi) sb[r] = NEGBIG;
            }
        }

        // ---- online softmax over the 32-token unit (r13 verbatim) ----
        float mx = fmaxf(fmaxf(fmaxf(sa[0], sa[1]), fmaxf(sa[2], sa[3])),
                         fmaxf(fmaxf(sb[0], sb[1]), fmaxf(sb[2], sb[3])));
        mx = fmaxf(mx, __shfl_xor(mx, 16));
        mx = fmaxf(mx, __shfl_xor(mx, 32));
        float mn = fmaxf(m_run, mx);
        float e  = __expf(m_run - mn);
        float pA[4], pB[4];
#pragma unroll
        for (int r = 0; r < 4; ++r) { pA[r] = __expf(sa[r] - mn); pB[r] = __expf(sb[r] - mn); }
        float sum = pA[0] + pA[1] + pA[2] + pA[3] + pB[0] + pB[1] + pB[2] + pB[3];
        sum += __shfl_xor(sum, 16);
        sum += __shfl_xor(sum, 32);
        l_run = l_run * e + sum;
        m_run = mn;
        f32x4 ef;
        ef.x = __shfl(e, (l & 48) + 0);
        ef.y = __shfl(e, (l & 48) + 1);
        ef.z = __shfl(e, (l & 48) + 2);
        ef.w = __shfl(e, (l & 48) + 3);
        o0 *= ef.x; o1 *= ef.y; o2 *= ef.z; o3 *= ef.w;

        // ---- P to per-wave LDS: D row = u*4+r (token-in-tile), col = head ----
        if (c < 4) {
#pragma unroll
            for (int r = 0; r < 4; ++r) {
                sP[w][u * 4 + r][c]      = pA[r];
                sP[w][16 + u * 4 + r][c] = pB[r];
            }
        }

        // ---- PV on VALU: halfwave owns 16 tokens, p broadcast from LDS ----
#pragma unroll
        for (int i = 0; i < 8; ++i) {
            f4 p4 = *(const f4*)&sP[w][hw2 * 16 + i][0];
            o0 += p4.x * vvA[i]; o1 += p4.y * vvA[i];
            o2 += p4.z * vvA[i]; o3 += p4.w * vvA[i];
        }
#pragma unroll
        for (int i = 0; i < 8; ++i) {
            f4 p4 = *(const f4*)&sP[w][hw2 * 16 + 8 + i][0];
            o0 += p4.x * vvB[i]; o1 += p4.y * vvB[i];
            o2 += p4.z * vvB[i]; o3 += p4.w * vvB[i];
        }
    }

    // ---- combine halfwaves (lanes il / il+32 hold the same dims) ----
    o0.x += __shfl_xor(o0.x, 32); o0.y += __shfl_xor(o0.y, 32);
    o0.z += __shfl_xor(o0.z, 32); o0.w += __shfl_xor(o0.w, 32);
    o1.x += __shfl_xor(o1.x, 32); o1.y += __shfl_xor(o1.y, 32);
    o1.z += __shfl_xor(o1.z, 32); o1.w += __shfl_xor(o1.w, 32);
    o2.x += __shfl_xor(o2.x, 32); o2.y += __shfl_xor(o2.y, 32);
    o2.z += __shfl_xor(o2.z, 32); o2.w += __shfl_xor(o2.w, 32);
    o3.x += __shfl_xor(o3.x, 32); o3.y += __shfl_xor(o3.y, 32);
    o3.z += __shfl_xor(o3.z, 32); o3.w += __shfl_xor(o3.w, 32);

    if (l < 4) { smw[w][l] = m_run; slw[w][l] = l_run; }
    if (l < 32) {
        const int d0 = l * 4;
        *(f4*)&sO[w][0][d0] = o0;
        *(f4*)&sO[w][1][d0] = o1;
        *(f4*)&sO[w][2][d0] = o2;
        *(f4*)&sO[w][3][d0] = o3;
    }
    __syncthreads();
#pragma unroll
    for (int rep = 0; rep < 2; ++rep) {
        int i = tid + 256 * rep;         // over 4 heads x 128 dims
        int g = i >> 7, d = i & 127;
        float M = fmaxf(fmaxf(smw[0][g], smw[1][g]), fmaxf(smw[2][g], smw[3][g]));
        float L = 0.f, O = 0.f;
#pragma unroll
        for (int wv = 0; wv < 4; ++wv) {
            float wgt = __expf(smw[wv][g] - M);
            L += wgt * slw[wv][g];
            O += wgt * sO[wv][g][d];
        }
        if (S == 1) {
            out[(size_t)b * (NQH * HD) + (size_t)(h * GQA + g) * HD + d] = O / L;
        } else {
            int pidx = blockIdx.x * 4 + g;
            po[(size_t)pidx * HD + d] = O;
            if (d == 0) { pm[pidx] = M; pl[pidx] = L; }
        }
    }
}

__global__ void combine_kernel(
    const float* __restrict__ pm, const float* __restrict__ pl,
    const float* __restrict__ po, float* __restrict__ out, int S)
{
    int i = blockIdx.x * blockDim.x + threadIdx.x;   // over B*NQH*HD
    int d  = i & 127;
    int qh = (i >> 7) & 31;
    int b  = i >> 12;
    int h  = qh >> 2;
    int g  = qh & 3;
    int base = ((b * NKVH + h) * S) * 4 + g;
    float M = NEGBIG;
    for (int s = 0; s < S; ++s) M = fmaxf(M, pm[base + s * 4]);
    float L = 0.f, O = 0.f;
    for (int s = 0; s < S; ++s) {
        float wgt = __expf(pm[base + s * 4] - M);
        L += wgt * pl[base + s * 4];
        O += wgt * po[(size_t)(base + s * 4) * HD + d];
    }
    out[i] = O / L;
}

extern "C" void kernel_launch(void* const* d_in, const int* in_sizes, int n_in,
                              void* d_out, int out_size, void* d_ws, size_t ws_size,
                              hipStream_t stream) {
    const float* q  = (const float*)d_in[0];
    const float* k  = (const float*)d_in[1];
    const float* v  = (const float*)d_in[2];
    const float* kc = (const float*)d_in[3];
    const float* vc = (const float*)d_in[4];
    const int*   bt = (const int*)d_in[5];
    int B  = in_sizes[0] / (NQH * HD);
    int nb = in_sizes[5] / B;
    int T  = nb * PBLK;

    float* out = (float*)d_out;
    char*  ws  = (char*)d_ws;

    size_t tabBytes = (size_t)(T + 1) * 128 * sizeof(float);
    size_t off = (tabBytes + 255) & ~(size_t)255;

    int S = 4;
    int nblk = B * NKVH * S;
    size_t pmB = (size_t)nblk * 4 * sizeof(float);
    size_t poB = (size_t)nblk * 4 * HD * sizeof(float);
    size_t need = off + 2 * pmB + poB;

    int useTable = (ws_size >= tabBytes) ? 1 : 0;
    if (ws_size < need) S = 1;

    float* tab = (float*)ws;
    float* pm  = (float*)(ws + off);
    float* pl  = (float*)(ws + off + pmB);
    float* po  = (float*)(ws + off + 2 * pmB);

    if (useTable) {
        int tot = (T + 1) * 64;
        rope_table_kernel<<<(tot + 255) / 256, 256, 0, stream>>>(tab, T);
    }
    paged_attn_kernel<<<B * NKVH * S, 256, 0, stream>>>(
        q, k, v, kc, vc, bt, tab, out, pm, pl, po, T, nb, S, useTable);
    if (S > 1) {
        int totalOut = B * NQH * HD;
        combine_kernel<<<(totalOut + 255) / 256, 256, 0, stream>>>(pm, pl, po, out, S);
    }
}

// Round 15
// 101.465 us; speedup vs baseline: 1.3390x; 1.3390x over previous
//
#include <hip/hip_runtime.h>
#include <math.h>

#define HD    128
#define NQH   32
#define NKVH  8
#define GQA   4
#define PBLK  16      // paged cache block size
#define MAXNB 512     // max block-table entries cached in LDS
#define BATCH 4       // tokens per inner iteration per half-wave

#define L2_10000 13.287712379549449f   // log2(10000)

typedef float f4 __attribute__((ext_vector_type(4)));
typedef float f2 __attribute__((ext_vector_type(2)));

__device__ __forceinline__ f4 ldnt4(const float* p) {
    return __builtin_nontemporal_load((const f4*)p);
}
__device__ __forceinline__ f2 ldnt2(const float* p) {
    return __builtin_nontemporal_load((const f2*)p);
}

// R9 champion structure (109us e2e: single kernel, no d_ws, recurrence rope)
// + batch-4 back-to-back loads + nontemporal K/V loads (zero-reuse stream;
// the one untried lever on the streaming-read rate). All compute structures
// r2-r14 land 109-137us e2e => memory-stream-bound; floor = 512MB/6.3TBps
// = 81us.
__global__ __launch_bounds__(1024) void paged_attn_kernel(
    const float* __restrict__ q,
    const float* __restrict__ kcur,
    const float* __restrict__ vcur,
    const float* __restrict__ kc,
    const float* __restrict__ vc,
    const int* __restrict__ bt,
    float* __restrict__ out,
    int T, int nb)
{
    const int b   = blockIdx.x >> 3;
    const int h   = blockIdx.x & 7;
    const int tid = threadIdx.x;
    const int hw  = tid >> 5;        // half-wave id 0..31
    const int il  = tid & 31;        // lane within half-wave
    const int d0v = il << 2;         // V/output dims [d0v, d0v+4)
    const int dk  = il << 1;         // K dims: {dk,dk+1} and {64+dk, 64+dk+1}

    // cache block table row in LDS
    __shared__ int sbt[MAXNB];
    const int* btrow = bt + (size_t)b * nb;
    if (nb <= MAXNB) {
        for (int i = tid; i < nb; i += 1024) sbt[i] = btrow[i];
        __syncthreads();
        btrow = sbt;
    }

    // this lane's two rope frequencies
    const float invf0 = exp2f(-(float)(dk)     * (L2_10000 / 64.0f));
    const float invf1 = exp2f(-(float)(dk + 1) * (L2_10000 / 64.0f));
    const float scale = 0.08838834764831845f;  // 128^-0.5

    // --- rope current q (4 GQA heads) at position T, scale folded in ---
    f4 qr[4];
    {
        float cT0, sT0, cT1, sT1;
        sincosf((float)T * invf0, &sT0, &cT0);
        sincosf((float)T * invf1, &sT1, &cT1);
        const float* qb = q + ((size_t)b * NQH + h * GQA) * HD;
#pragma unroll
        for (int g = 0; g < 4; ++g) {
            f2 xlo = *(const f2*)(qb + (size_t)g * HD + dk);
            f2 xhi = *(const f2*)(qb + (size_t)g * HD + 64 + dk);
            qr[g].x = (xlo.x * cT0 - xhi.x * sT0) * scale;
            qr[g].y = (xlo.y * cT1 - xhi.y * sT1) * scale;
            qr[g].z = (xhi.x * cT0 + xlo.x * sT0) * scale;
            qr[g].w = (xhi.y * cT1 + xlo.y * sT1) * scale;
        }
    }

    // --- rope phase recurrence: state at token hw; rotor advances 32 ---
    float c0, s0c, c1, s1c, C0, S0, C1, S1;
    sincosf((float)hw * invf0, &s0c, &c0);
    sincosf((float)hw * invf1, &s1c, &c1);
    sincosf(32.0f * invf0, &S0, &C0);
    sincosf(32.0f * invf1, &S1, &C1);

    float m[4] = {-INFINITY, -INFINITY, -INFINITY, -INFINITY};
    float l[4] = {0.f, 0.f, 0.f, 0.f};
    f4 o[4] = {};

    const float* kcurp = kcur + ((size_t)b * NKVH + h) * HD;
    const float* vcurp = vcur + ((size_t)b * NKVH + h) * HD;

    // --- main loop: half-wave takes BATCH tokens per iteration: t0+32j ---
    for (int t0 = hw; t0 <= T; t0 += 32 * BATCH) {
        f2 klo[BATCH], khi[BATCH];
        f4 vv[BATCH];
        bool valid[BATCH];
        // issue all loads back-to-back (12 VMEM in flight), nontemporal
#pragma unroll
        for (int j = 0; j < BATCH; ++j) {
            int tj = t0 + 32 * j;
            valid[j] = (tj <= T);
            int tc = valid[j] ? tj : hw;          // clamped: always in-bounds
            const float *kb, *vb;
            if (tc == T) { kb = kcurp; vb = vcurp; }
            else {
                int blk = btrow[tc >> 4];
                size_t off = (((size_t)blk * PBLK + (tc & (PBLK - 1))) * NKVH + h) * HD;
                kb = kc + off; vb = vc + off;
            }
            klo[j] = ldnt2(kb + dk);
            khi[j] = ldnt2(kb + 64 + dk);
            vv[j]  = ldnt4(vb + d0v);
        }

        // rope + dot partials for all BATCH tokens
        float v[BATCH][4];
#pragma unroll
        for (int j = 0; j < BATCH; ++j) {
            f4 kr;
            kr.x = klo[j].x * c0 - khi[j].x * s0c;
            kr.y = klo[j].y * c1 - khi[j].y * s1c;
            kr.z = khi[j].x * c0 + klo[j].x * s0c;
            kr.w = khi[j].y * c1 + klo[j].y * s1c;
            {   // advance phase by 32 positions (complex multiply)
                float nc0 = c0 * C0 - s0c * S0, ns0 = s0c * C0 + c0 * S0;
                float nc1 = c1 * C1 - s1c * S1, ns1 = s1c * C1 + c1 * S1;
                c0 = nc0; s0c = ns0; c1 = nc1; s1c = ns1;
            }
#pragma unroll
            for (int g = 0; g < 4; ++g)
                v[j][g] = qr[g].x * kr.x + qr[g].y * kr.y
                        + qr[g].z * kr.z + qr[g].w * kr.w;
        }

        // butterfly reduce: 16 independent shuffles per stage, 5 stages
#pragma unroll
        for (int msk = 16; msk >= 1; msk >>= 1) {
#pragma unroll
            for (int j = 0; j < BATCH; ++j) {
#pragma unroll
                for (int g = 0; g < 4; ++g)
                    v[j][g] += __shfl_xor(v[j][g], msk);
            }
        }

        // online softmax updates
#pragma unroll
        for (int j = 0; j < BATCH; ++j) {
#pragma unroll
            for (int g = 0; g < 4; ++g) {
                float sc = valid[j] ? v[j][g] : -INFINITY;
                if (sc > m[g]) {                 // lazy rescale: rare
                    float corr = __expf(m[g] - sc);
                    l[g] *= corr;
                    o[g] *= corr;
                    m[g] = sc;
                }
                float p = __expf(sc - m[g]);     // exp(-inf)=0 for invalid
                l[g] += p;
                o[g] += p * vv[j];
            }
        }
    }

    // --- combine the two half-waves of each wave ---
#pragma unroll
    for (int g = 0; g < 4; ++g) {
        float mo = __shfl_xor(m[g], 32);
        float M  = fmaxf(m[g], mo);
        float w  = (m[g] > -INFINITY) ? __expf(m[g] - M) : 0.f;
        float lw = l[g] * w;
        float Lc = lw + __shfl_xor(lw, 32);
        f4 ow = o[g] * w;
        f4 Oc;
        Oc.x = ow.x + __shfl_xor(ow.x, 32);
        Oc.y = ow.y + __shfl_xor(ow.y, 32);
        Oc.z = ow.z + __shfl_xor(ow.z, 32);
        Oc.w = ow.w + __shfl_xor(ow.w, 32);
        m[g] = M; l[g] = Lc; o[g] = Oc;
    }

    // --- cross-wave flash combine via LDS ---
    __shared__ float lm[16][4];
    __shared__ float ll[16][4];
    __shared__ float lodata[16][4][HD];
    const int w = tid >> 6;
    if ((tid & 32) == 0) {
        if (il == 0) {
#pragma unroll
            for (int g = 0; g < 4; ++g) { lm[w][g] = m[g]; ll[w][g] = l[g]; }
        }
#pragma unroll
        for (int g = 0; g < 4; ++g)
            *(f4*)(&lodata[w][g][d0v]) = o[g];
    }
    __syncthreads();

    if (tid < 512) {
        int g = tid >> 7;
        int d = tid & 127;
        float M = -INFINITY;
#pragma unroll
        for (int i = 0; i < 16; ++i) M = fmaxf(M, lm[i][g]);
        float L = 0.f, O = 0.f;
#pragma unroll
        for (int i = 0; i < 16; ++i) {
            float wgt = __expf(lm[i][g] - M);
            L += wgt * ll[i][g];
            O += wgt * lodata[i][g][d];
        }
        out[(size_t)b * (NQH * HD) + (size_t)(h * GQA + g) * HD + d] = O / L;
    }
}

extern "C" void kernel_launch(void* const* d_in, const int* in_sizes, int n_in,
                              void* d_out, int out_size, void* d_ws, size_t ws_size,
                              hipStream_t stream) {
    const float* q  = (const float*)d_in[0];
    const float* k  = (const float*)d_in[1];
    const float* v  = (const float*)d_in[2];
    const float* kc = (const float*)d_in[3];
    const float* vc = (const float*)d_in[4];
    const int*   bt = (const int*)d_in[5];
    int B  = in_sizes[0] / (NQH * HD);
    int nb = in_sizes[5] / B;
    int T  = nb * PBLK;

    float* out = (float*)d_out;
    paged_attn_kernel<<<B * NKVH, 1024, 0, stream>>>(q, k, v, kc, vc, bt, out, T, nb);
}